// Round 6
// baseline (350.134 us; speedup 1.0000x reference)
//
#include <hip/hip_runtime.h>
#include <hip/hip_bf16.h>

#define LRELU(t) ((t) > 0.0f ? (t) : 0.01f * (t))
#define LOG2E 1.4426950408889634f

typedef __attribute__((ext_vector_type(8))) short bf16x8;
typedef __attribute__((ext_vector_type(4))) float f32x4;

__device__ __forceinline__ unsigned short f2bf(float f) {
  unsigned u = __float_as_uint(f);
  u += 0x7fff + ((u >> 16) & 1);  // round-to-nearest-even
  return (unsigned short)(u >> 16);
}
__device__ __forceinline__ float bflo(unsigned u) { return __uint_as_float(u << 16); }
__device__ __forceinline__ float bfhi(unsigned u) { return __uint_as_float(u & 0xffff0000u); }

// Stored-word permutation: stored u32 word s (within a 128-word half-row) holds
// logical dims (pilo(s), pilo(s)+16).  Derived from MFMA C-layout + uint2 packing.
__device__ __forceinline__ int pilo(int s) {
  return ((s >> 5) << 6) + ((s & 1) << 5) + ((s >> 1) & 15);
}

// ---------- weight transpose + bf16 convert (one-shot, tiny) ----------
// WtA[256][128] = [W_emb^T ; Wa1^T] (logical col order, logical k)
// WtU[128][128] = W_upd^T with k permuted by pi (to consume permuted msgb)
__global__ __launch_bounds__(256) void wtrans_kernel(
    const float* __restrict__ W_emb, const float* __restrict__ Wa1,
    const float* __restrict__ W_upd, unsigned short* __restrict__ WtA,
    unsigned short* __restrict__ WtU) {
  int i = blockIdx.x * 256 + threadIdx.x;
  if (i < 32768) {
    int n = i >> 7, k = i & 127;
    float v = (n < 128) ? W_emb[k * 128 + n] : Wa1[k * 128 + (n - 128)];
    WtA[i] = f2bf(v);
  } else if (i < 49152) {
    int j = i - 32768;
    int n = j >> 7, k_st = j & 127;
    int s = k_st >> 1;
    int L = pilo(s) + ((k_st & 1) << 4);
    WtU[j] = f2bf(W_upd[L * 128 + n]);
  }
}

// ---------- MFMA GEMM 1+2 fused: embP[M][128 u32] = bf16(x @ [W_emb|Wa1]), permuted ----------
// Block = 4 waves, tile 64 rows x 256 logical cols (wave w: cols w*64).
// Stores: lane packs (nf=2ph, 2ph+1) col pair into u32; uint2 per (mf,r) -> coalesced 128B lines.
__global__ __launch_bounds__(256) void gemm_embP_kernel(
    const float* __restrict__ A, const unsigned short* __restrict__ Wt,
    const float* __restrict__ b_emb, unsigned* __restrict__ embP, int M) {
  const int lane = threadIdx.x & 63;
  const int w = threadIdx.x >> 6;
  const int row0 = blockIdx.x * 64;
  const int ncol0 = w * 64;
  const int lr = lane & 15;
  const int lg = lane >> 4;
  f32x4 acc[4][4];
#pragma unroll
  for (int mf = 0; mf < 4; ++mf)
#pragma unroll
    for (int nf = 0; nf < 4; ++nf) acc[mf][nf] = (f32x4){0.f, 0.f, 0.f, 0.f};

#pragma unroll
  for (int ks = 0; ks < 4; ++ks) {
    const int k0 = ks * 32 + lg * 8;
    bf16x8 bfr[4];
#pragma unroll
    for (int nf = 0; nf < 4; ++nf)
      bfr[nf] = *reinterpret_cast<const bf16x8*>(Wt + (size_t)(ncol0 + nf * 16 + lr) * 128 + k0);
    bf16x8 afr[4];
#pragma unroll
    for (int mf = 0; mf < 4; ++mf) {
      int row = row0 + mf * 16 + lr;
      if (row >= M) row = M - 1;
      const float* ap = A + (size_t)row * 128 + k0;
      float4 a0 = *reinterpret_cast<const float4*>(ap);
      float4 a1 = *reinterpret_cast<const float4*>(ap + 4);
      bf16x8 t;
      t[0] = (short)f2bf(a0.x); t[1] = (short)f2bf(a0.y);
      t[2] = (short)f2bf(a0.z); t[3] = (short)f2bf(a0.w);
      t[4] = (short)f2bf(a1.x); t[5] = (short)f2bf(a1.y);
      t[6] = (short)f2bf(a1.z); t[7] = (short)f2bf(a1.w);
      afr[mf] = t;
    }
#pragma unroll
    for (int mf = 0; mf < 4; ++mf)
#pragma unroll
      for (int nf = 0; nf < 4; ++nf)
        acc[mf][nf] =
            __builtin_amdgcn_mfma_f32_16x16x32_bf16(afr[mf], bfr[nf], acc[mf][nf], 0, 0, 0);
  }
  // bias (emb half only: logical cols < 128, i.e. waves 0,1)
  float blo[2] = {0.f, 0.f}, bhi[2] = {0.f, 0.f};
  if (ncol0 < 128) {
#pragma unroll
    for (int ph = 0; ph < 2; ++ph) {
      int lo = ncol0 + 32 * ph + lr;
      blo[ph] = b_emb[lo];
      bhi[ph] = b_emb[lo + 16];
    }
  }
#pragma unroll
  for (int mf = 0; mf < 4; ++mf) {
#pragma unroll
    for (int r = 0; r < 4; ++r) {
      int row = row0 + mf * 16 + lg * 4 + r;
      if (row < M) {
        unsigned w0 = (unsigned)f2bf(acc[mf][0][r] + blo[0]) |
                      ((unsigned)f2bf(acc[mf][1][r] + bhi[0]) << 16);
        unsigned w1 = (unsigned)f2bf(acc[mf][2][r] + blo[1]) |
                      ((unsigned)f2bf(acc[mf][3][r] + bhi[1]) << 16);
        *reinterpret_cast<uint2*>(embP + (size_t)row * 128 + w * 32 + lr * 2) =
            make_uint2(w0, w1);
      }
    }
  }
}

// ---------- MFMA GEMM 3: out[M x 128](f32) = msgb(bf16, permuted) @ W_upd + b_upd ----------
__global__ __launch_bounds__(256) void gemm_out_kernel(
    const unsigned short* __restrict__ Ab, const unsigned short* __restrict__ Wt,
    const float* __restrict__ b_upd, float* __restrict__ Cout, int M) {
  const int lane = threadIdx.x & 63;
  const int w = threadIdx.x >> 6;
  const int row0 = blockIdx.x * 128 + (w >> 1) * 64;
  const int ncol0 = (w & 1) * 64;
  const int lr = lane & 15;
  const int lg = lane >> 4;
  f32x4 acc[4][4];
#pragma unroll
  for (int mf = 0; mf < 4; ++mf)
#pragma unroll
    for (int nf = 0; nf < 4; ++nf) acc[mf][nf] = (f32x4){0.f, 0.f, 0.f, 0.f};

#pragma unroll
  for (int ks = 0; ks < 4; ++ks) {
    const int k0 = ks * 32 + lg * 8;
    bf16x8 bfr[4];
#pragma unroll
    for (int nf = 0; nf < 4; ++nf)
      bfr[nf] = *reinterpret_cast<const bf16x8*>(Wt + (size_t)(ncol0 + nf * 16 + lr) * 128 + k0);
    bf16x8 afr[4];
#pragma unroll
    for (int mf = 0; mf < 4; ++mf) {
      int row = row0 + mf * 16 + lr;
      if (row >= M) row = M - 1;
      afr[mf] = *reinterpret_cast<const bf16x8*>(Ab + (size_t)row * 128 + k0);
    }
#pragma unroll
    for (int mf = 0; mf < 4; ++mf)
#pragma unroll
      for (int nf = 0; nf < 4; ++nf)
        acc[mf][nf] =
            __builtin_amdgcn_mfma_f32_16x16x32_bf16(afr[mf], bfr[nf], acc[mf][nf], 0, 0, 0);
  }
#pragma unroll
  for (int nf = 0; nf < 4; ++nf) {
    int col = ncol0 + nf * 16 + lr;
    float bv = b_upd[col];
#pragma unroll
    for (int mf = 0; mf < 4; ++mf) {
      int rowb = row0 + mf * 16 + lg * 4;
#pragma unroll
      for (int r = 0; r < 4; ++r) {
        int row = rowb + r;
        if (row < M) Cout[(size_t)row * 128 + col] = acc[mf][nf][r] + bv;
      }
    }
  }
}

// ---------- zero ----------
__global__ void zero_kernel(int* __restrict__ p, int n) {
  int i = blockIdx.x * blockDim.x + threadIdx.x;
  if (i < n) p[i] = 0;
}

// ---------- histogram of col ----------
__global__ void count_kernel(const int* __restrict__ col, int* __restrict__ counts, int E) {
  int e = blockIdx.x * blockDim.x + threadIdx.x;
  if (e < E) atomicAdd(&counts[col[e]], 1);
}

// ---------- 3-kernel exclusive scan over N1 = N+1 elements ----------
__global__ __launch_bounds__(1024) void scan1_kernel(const int* __restrict__ counts,
                                                     int* __restrict__ offsets,
                                                     int* __restrict__ bsum, int N, int N1) {
  __shared__ int sh[1024];
  int tid = threadIdx.x;
  int i = blockIdx.x * 1024 + tid;
  int v = (i < N) ? counts[i] : 0;
  sh[tid] = v;
  __syncthreads();
  for (int off = 1; off < 1024; off <<= 1) {
    int tv = (tid >= off) ? sh[tid - off] : 0;
    __syncthreads();
    sh[tid] += tv;
    __syncthreads();
  }
  if (i < N1) offsets[i] = sh[tid] - v;
  if (tid == 1023) bsum[blockIdx.x] = sh[1023];
}

__global__ __launch_bounds__(128) void scan2_kernel(int* __restrict__ bsum, int NB) {
  __shared__ int sh[128];
  int tid = threadIdx.x;
  int v = (tid < NB) ? bsum[tid] : 0;
  sh[tid] = v;
  __syncthreads();
  for (int off = 1; off < 128; off <<= 1) {
    int tv = (tid >= off) ? sh[tid - off] : 0;
    __syncthreads();
    sh[tid] += tv;
    __syncthreads();
  }
  if (tid < NB) bsum[tid] = sh[tid] - v;
}

__global__ __launch_bounds__(1024) void scan3_kernel(int* __restrict__ offsets,
                                                     const int* __restrict__ bsum,
                                                     int* __restrict__ cursor, int N, int N1) {
  int i = blockIdx.x * 1024 + threadIdx.x;
  if (i < N1) {
    int o = offsets[i] + bsum[blockIdx.x];
    offsets[i] = o;
    if (i < N) cursor[i] = o;
  }
}

// ---------- prep: a_self (in exp2 domain, ba2 dropped) + permuted ba1/Wa2 pair tables ----------
__global__ __launch_bounds__(64) void prep_kernel(const float* __restrict__ ba1,
                                                  const float* __restrict__ Wa2,
                                                  float* __restrict__ a_self,
                                                  float2* __restrict__ ba1p,
                                                  float2* __restrict__ wa2p) {
  int l = threadIdx.x;  // 0..63
  int d = pilo(l);
  ba1p[l] = make_float2(ba1[d], ba1[d + 16]);
  wa2p[l] = make_float2(Wa2[d] * LOG2E, Wa2[d + 16] * LOG2E);
  float t1 = ba1[l], t2 = ba1[l + 64];
  float v = LRELU(t1) * Wa2[l] + LRELU(t2) * Wa2[l + 64];
#pragma unroll
  for (int off = 32; off > 0; off >>= 1) v += __shfl_xor(v, off);
  if (l == 0) *a_self = v * LOG2E;
}

// ---------- CSR build: scatter rol values grouped by col ----------
__global__ void scatter_kernel(const int* __restrict__ rol, const int* __restrict__ col,
                               int* __restrict__ cursor, int* __restrict__ csr_rol, int E) {
  int e = blockIdx.x * blockDim.x + threadIdx.x;
  if (e < E) {
    int pos = atomicAdd(&cursor[col[e]], 1);
    csr_rol[pos] = rol[e];
  }
}

// ---------- fused flash node kernel: wave/node, 4 edges per batch in 16-lane groups ----------
// embP row: words 0..63 = emb pairs (permuted), 64..127 = P pairs (permuted)
__global__ __launch_bounds__(256) void fused_kernel(
    const int* __restrict__ offsets, const int* __restrict__ csr_rol,
    const unsigned* __restrict__ embP, const float2* __restrict__ ba1p,
    const float2* __restrict__ wa2p, const float* __restrict__ a_self_p,
    unsigned* __restrict__ msgb, int N, int nwt) {
  const int lane = threadIdx.x & 63;
  const int q = lane & 15;  // dim-quad within group
  const int wid = blockIdx.x * (blockDim.x >> 6) + (threadIdx.x >> 6);
  const int g = lane >> 4;  // edge-group id
  float2 w4[4], b4[4];
#pragma unroll
  for (int k = 0; k < 4; ++k) {
    w4[k] = wa2p[q * 4 + k];
    b4[k] = ba1p[q * 4 + k];
  }
  const float aself = *a_self_p;

  for (int n = wid; n < N; n += nwt) {
    int j0 = offsets[n], j1 = offsets[n + 1];
    const unsigned* rowp = embP + (size_t)n * 128;
    unsigned ue = rowp[lane];
    uint4 pc4 = *reinterpret_cast<const uint4*>(rowp + 64 + q * 4);
    // pm = P_col - ba1 at this lane's 8 permuted dims
    float pm0 = bflo(pc4.x) - b4[0].x, pm1 = bfhi(pc4.x) - b4[0].y;
    float pm2 = bflo(pc4.y) - b4[1].x, pm3 = bfhi(pc4.y) - b4[1].y;
    float pm4 = bflo(pc4.z) - b4[2].x, pm5 = bfhi(pc4.z) - b4[2].y;
    float pm6 = bflo(pc4.w) - b4[3].x, pm7 = bfhi(pc4.w) - b4[3].y;
    float m = aself, s = 1.0f;
    float ax = bflo(ue), ay = bfhi(ue);

    for (int j = j0; j < j1; j += 4) {
      int jj = j + g;
      int jc = (jj < j1) ? jj : (j1 - 1);
      int r = csr_rol[jc];
      int r0 = __shfl(r, 0), r1 = __shfl(r, 16), r2 = __shfl(r, 32), r3 = __shfl(r, 48);
      unsigned pe0 = embP[(size_t)r0 * 128 + lane];
      unsigned pe1 = embP[(size_t)r1 * 128 + lane];
      unsigned pe2 = embP[(size_t)r2 * 128 + lane];
      unsigned pe3 = embP[(size_t)r3 * 128 + lane];
      uint4 pp4 = *reinterpret_cast<const uint4*>(embP + (size_t)r * 128 + 64 + q * 4);
      // partial logit over my 8 dims (lrelu = max(t, 0.01t)), weights pre-scaled by log2e
      float t, v;
      t = bflo(pp4.x) - pm0; t = fmaxf(t, 0.01f * t); v = t * w4[0].x;
      t = bfhi(pp4.x) - pm1; t = fmaxf(t, 0.01f * t); v += t * w4[0].y;
      t = bflo(pp4.y) - pm2; t = fmaxf(t, 0.01f * t); v += t * w4[1].x;
      t = bfhi(pp4.y) - pm3; t = fmaxf(t, 0.01f * t); v += t * w4[1].y;
      t = bflo(pp4.z) - pm4; t = fmaxf(t, 0.01f * t); v += t * w4[2].x;
      t = bfhi(pp4.z) - pm5; t = fmaxf(t, 0.01f * t); v += t * w4[2].y;
      t = bflo(pp4.w) - pm6; t = fmaxf(t, 0.01f * t); v += t * w4[3].x;
      t = bfhi(pp4.w) - pm7; t = fmaxf(t, 0.01f * t); v += t * w4[3].y;
      // 16-lane reduce (4 edges reduced simultaneously)
      v += __shfl_xor(v, 1);
      v += __shfl_xor(v, 2);
      v += __shfl_xor(v, 4);
      v += __shfl_xor(v, 8);
      float v0 = __shfl(v, 0);
      float s1 = __shfl(v, 16), s2 = __shfl(v, 32), s3 = __shfl(v, 48);
      float v1 = (j + 1 < j1) ? s1 : -1e30f;
      float v2 = (j + 2 < j1) ? s2 : -1e30f;
      float v3 = (j + 3 < j1) ? s3 : -1e30f;
      // batched online-softmax update (exp2 domain)
      float nm = fmaxf(fmaxf(m, fmaxf(v0, v1)), fmaxf(v2, v3));
      float cc = __builtin_exp2f(m - nm);
      float e0 = __builtin_exp2f(v0 - nm), e1 = __builtin_exp2f(v1 - nm);
      float e2 = __builtin_exp2f(v2 - nm), e3 = __builtin_exp2f(v3 - nm);
      s = s * cc + ((e0 + e1) + (e2 + e3));
      ax = ax * cc + ((e0 * bflo(pe0) + e1 * bflo(pe1)) + (e2 * bflo(pe2) + e3 * bflo(pe3)));
      ay = ay * cc + ((e0 * bfhi(pe0) + e1 * bfhi(pe1)) + (e2 * bfhi(pe2) + e3 * bfhi(pe3)));
      m = nm;
    }
    float inv = 1.0f / s;
    msgb[(size_t)n * 64 + lane] =
        (unsigned)f2bf(ax * inv) | ((unsigned)f2bf(ay * inv) << 16);
  }
}

extern "C" void kernel_launch(void* const* d_in, const int* in_sizes, int n_in,
                              void* d_out, int out_size, void* d_ws, size_t ws_size,
                              hipStream_t stream) {
  const float* x     = (const float*)d_in[0];
  const int*   ei    = (const int*)d_in[1];
  const float* W_emb = (const float*)d_in[2];
  const float* b_emb = (const float*)d_in[3];
  const float* Wa1   = (const float*)d_in[4];
  const float* ba1   = (const float*)d_in[5];
  const float* Wa2   = (const float*)d_in[6];
  // d_in[7] = ba2: cancels in segment softmax, unused
  const float* W_upd = (const float*)d_in[8];
  const float* b_upd = (const float*)d_in[9];
  float* out = (float*)d_out;

  const int N = in_sizes[0] / 128;
  const int E = in_sizes[1] / 2;
  const int* rol = ei;
  const int* col = ei + E;

  // workspace carve (all 256B aligned)
  char* base = (char*)d_ws;
  size_t off = 0;
  auto carve = [&](size_t bytes) {
    void* p = base + off;
    off = (off + bytes + 255) & ~(size_t)255;
    return p;
  };
  unsigned* embP   = (unsigned*)carve((size_t)N * 128 * 4);  // [emb|P] permuted bf16 pairs
  unsigned* msgb   = (unsigned*)carve((size_t)N * 64 * 4);   // msg permuted bf16 pairs
  unsigned short* WtA = (unsigned short*)carve(256 * 128 * 2);
  unsigned short* WtU = (unsigned short*)carve(128 * 128 * 2);
  float2*   ba1p   = (float2*)carve(64 * 8);
  float2*   wa2p   = (float2*)carve(64 * 8);
  int*      csr_rol= (int*)carve((size_t)E * 4);
  float*    a_self = (float*)carve(16);
  int*      counts = (int*)carve((size_t)N * 4);
  int*      offsets= (int*)carve((size_t)(N + 1) * 4);
  int*      cursor = (int*)carve((size_t)N * 4);
  int*      bsum   = (int*)carve(128 * 4);
  (void)ws_size;

  const int N1 = N + 1;
  const int NB = (N1 + 1023) / 1024;  // 98 for N=100000 (must be <=128)
  const int SBLK = 2048;              // grid-stride blocks (8192 waves)
  const int NWT = SBLK * 4;

  zero_kernel<<<(N + 255) / 256, 256, 0, stream>>>(counts, N);
  wtrans_kernel<<<192, 256, 0, stream>>>(W_emb, Wa1, W_upd, WtA, WtU);

  gemm_embP_kernel<<<(N + 63) / 64, 256, 0, stream>>>(x, WtA, b_emb, embP, N);

  count_kernel<<<(E + 255) / 256, 256, 0, stream>>>(col, counts, E);
  scan1_kernel<<<NB, 1024, 0, stream>>>(counts, offsets, bsum, N, N1);
  scan2_kernel<<<1, 128, 0, stream>>>(bsum, NB);
  scan3_kernel<<<NB, 1024, 0, stream>>>(offsets, bsum, cursor, N, N1);
  prep_kernel<<<1, 64, 0, stream>>>(ba1, Wa2, a_self, ba1p, wa2p);
  scatter_kernel<<<(E + 255) / 256, 256, 0, stream>>>(rol, col, cursor, csr_rol, E);

  fused_kernel<<<SBLK, 256, 0, stream>>>(offsets, csr_rol, embP, ba1p, wa2p, a_self, msgb, N,
                                         NWT);

  gemm_out_kernel<<<(N + 127) / 128, 256, 0, stream>>>((const unsigned short*)msgb, WtU, b_upd,
                                                       out, N);
}

// Round 9
// 336.408 us; speedup vs baseline: 1.0408x; 1.0408x over previous
//
#include <hip/hip_runtime.h>
#include <hip/hip_bf16.h>
#include <hip/hip_fp16.h>

#define LRELU(t) ((t) > 0.0f ? (t) : 0.01f * (t))
#define LOG2E 1.4426950408889634f

typedef __attribute__((ext_vector_type(8))) _Float16 half8;
typedef __attribute__((ext_vector_type(2))) _Float16 half2t;
typedef __attribute__((ext_vector_type(2))) __fp16 fp16x2;
typedef __attribute__((ext_vector_type(4))) float f32x4;

union H8U4 { half8 h; uint4 u; half2t p[4]; };

__device__ __forceinline__ unsigned pkrtz(float a, float b) {
  union { fp16x2 h; unsigned u; } r;
  r.h = __builtin_amdgcn_cvt_pkrtz(a, b);
  return r.u;
}

// Stored-word permutation: stored u32 word s (within a 64-word half-row) holds
// logical dims (pilo(s), pilo(s)+16).  Derived from MFMA C-layout + uint2 packing.
__device__ __forceinline__ int pilo(int s) {
  return ((s >> 5) << 6) + ((s & 1) << 5) + ((s >> 1) & 15);
}

#if __has_builtin(__builtin_amdgcn_fdot2)
#define FDOT2(a, b, c) __builtin_amdgcn_fdot2((a), (b), (c), false)
#else
#define FDOT2(a, b, c) ((c) + (float)(a)[0] * (float)(b)[0] + (float)(a)[1] * (float)(b)[1])
#endif

// ---------- x -> f16 convert (elementwise, BW-bound) ----------
__global__ __launch_bounds__(256) void xcvt_kernel(const float4* __restrict__ x,
                                                   uint4* __restrict__ x16, int n8) {
  int i = blockIdx.x * 256 + threadIdx.x;
  if (i >= n8) return;
  float4 a = x[2 * i], b = x[2 * i + 1];
  uint4 o;
  o.x = pkrtz(a.x, a.y);
  o.y = pkrtz(a.z, a.w);
  o.z = pkrtz(b.x, b.y);
  o.w = pkrtz(b.z, b.w);
  x16[i] = o;
}

// ---------- weight transpose + f16 convert (one-shot, tiny) ----------
// WtA[256][128] = [W_emb^T ; Wa1^T] (logical k).  WtU[128][128] = W_upd^T, k permuted by pilo.
__global__ __launch_bounds__(256) void wtrans_kernel(
    const float* __restrict__ W_emb, const float* __restrict__ Wa1,
    const float* __restrict__ W_upd, _Float16* __restrict__ WtA,
    _Float16* __restrict__ WtU) {
  int i = blockIdx.x * 256 + threadIdx.x;
  if (i < 32768) {
    int n = i >> 7, k = i & 127;
    float v = (n < 128) ? W_emb[k * 128 + n] : Wa1[k * 128 + (n - 128)];
    WtA[i] = (_Float16)v;
  } else if (i < 49152) {
    int j = i - 32768;
    int n = j >> 7, k_st = j & 127;
    int s = k_st >> 1;
    int L = pilo(s) + ((k_st & 1) << 4);
    WtU[j] = (_Float16)W_upd[L * 128 + n];
  }
}

// ---------- MFMA GEMM 1+2: embP[M][128 u32] = f16(x @ [W_emb|Wa1]) permuted-pair packed ----
// Block = 4 waves over 32 rows x 256 logical cols (wave w: cols w*64).  A,B f16 dwordx4 frags.
__global__ __launch_bounds__(256) void gemm_embP_kernel(
    const _Float16* __restrict__ A, const _Float16* __restrict__ Wt,
    const float* __restrict__ b_emb, unsigned* __restrict__ embP, int M) {
  const int lane = threadIdx.x & 63;
  const int w = threadIdx.x >> 6;
  const int row0 = blockIdx.x * 32;
  const int ncol0 = w * 64;
  const int lr = lane & 15;
  const int lg = lane >> 4;
  f32x4 acc[2][4];
#pragma unroll
  for (int mf = 0; mf < 2; ++mf)
#pragma unroll
    for (int nf = 0; nf < 4; ++nf) acc[mf][nf] = (f32x4){0.f, 0.f, 0.f, 0.f};

#pragma unroll
  for (int ks = 0; ks < 4; ++ks) {
    const int k0 = ks * 32 + lg * 8;
    half8 bfr[4];
#pragma unroll
    for (int nf = 0; nf < 4; ++nf)
      bfr[nf] = *reinterpret_cast<const half8*>(Wt + (size_t)(ncol0 + nf * 16 + lr) * 128 + k0);
    half8 afr[2];
#pragma unroll
    for (int mf = 0; mf < 2; ++mf) {
      int row = row0 + mf * 16 + lr;
      if (row >= M) row = M - 1;
      afr[mf] = *reinterpret_cast<const half8*>(A + (size_t)row * 128 + k0);
    }
#pragma unroll
    for (int mf = 0; mf < 2; ++mf)
#pragma unroll
      for (int nf = 0; nf < 4; ++nf)
        acc[mf][nf] =
            __builtin_amdgcn_mfma_f32_16x16x32_f16(afr[mf], bfr[nf], acc[mf][nf], 0, 0, 0);
  }
  float blo[2] = {0.f, 0.f}, bhi[2] = {0.f, 0.f};
  if (ncol0 < 128) {
#pragma unroll
    for (int ph = 0; ph < 2; ++ph) {
      int lo = ncol0 + 32 * ph + lr;
      blo[ph] = b_emb[lo];
      bhi[ph] = b_emb[lo + 16];
    }
  }
#pragma unroll
  for (int mf = 0; mf < 2; ++mf) {
#pragma unroll
    for (int r = 0; r < 4; ++r) {
      int row = row0 + mf * 16 + lg * 4 + r;
      if (row < M) {
        unsigned w0 = pkrtz(acc[mf][0][r] + blo[0], acc[mf][1][r] + bhi[0]);
        unsigned w1 = pkrtz(acc[mf][2][r] + blo[1], acc[mf][3][r] + bhi[1]);
        *reinterpret_cast<uint2*>(embP + (size_t)row * 128 + w * 32 + lr * 2) =
            make_uint2(w0, w1);
      }
    }
  }
}

// ---------- MFMA GEMM 3: out[M x 128](f32) = msgb(f16, permuted) @ W_upd + b_upd ----------
// Block = 4 waves over 64 rows x 128 cols (wave w: rows (w>>1)*32, cols (w&1)*64).
__global__ __launch_bounds__(256) void gemm_out_kernel(
    const _Float16* __restrict__ Ab, const _Float16* __restrict__ Wt,
    const float* __restrict__ b_upd, float* __restrict__ Cout, int M) {
  const int lane = threadIdx.x & 63;
  const int w = threadIdx.x >> 6;
  const int row0 = blockIdx.x * 64 + (w >> 1) * 32;
  const int ncol0 = (w & 1) * 64;
  const int lr = lane & 15;
  const int lg = lane >> 4;
  f32x4 acc[2][4];
#pragma unroll
  for (int mf = 0; mf < 2; ++mf)
#pragma unroll
    for (int nf = 0; nf < 4; ++nf) acc[mf][nf] = (f32x4){0.f, 0.f, 0.f, 0.f};

#pragma unroll
  for (int ks = 0; ks < 4; ++ks) {
    const int k0 = ks * 32 + lg * 8;
    half8 bfr[4];
#pragma unroll
    for (int nf = 0; nf < 4; ++nf)
      bfr[nf] = *reinterpret_cast<const half8*>(Wt + (size_t)(ncol0 + nf * 16 + lr) * 128 + k0);
    half8 afr[2];
#pragma unroll
    for (int mf = 0; mf < 2; ++mf) {
      int row = row0 + mf * 16 + lr;
      if (row >= M) row = M - 1;
      afr[mf] = *reinterpret_cast<const half8*>(Ab + (size_t)row * 128 + k0);
    }
#pragma unroll
    for (int mf = 0; mf < 2; ++mf)
#pragma unroll
      for (int nf = 0; nf < 4; ++nf)
        acc[mf][nf] =
            __builtin_amdgcn_mfma_f32_16x16x32_f16(afr[mf], bfr[nf], acc[mf][nf], 0, 0, 0);
  }
#pragma unroll
  for (int nf = 0; nf < 4; ++nf) {
    int col = ncol0 + nf * 16 + lr;
    float bv = b_upd[col];
#pragma unroll
    for (int mf = 0; mf < 2; ++mf) {
      int rowb = row0 + mf * 16 + lg * 4;
#pragma unroll
      for (int r = 0; r < 4; ++r) {
        int row = rowb + r;
        if (row < M) Cout[(size_t)row * 128 + col] = acc[mf][nf][r] + bv;
      }
    }
  }
}

// ---------- zero ----------
__global__ void zero_kernel(int* __restrict__ p, int n) {
  int i = blockIdx.x * blockDim.x + threadIdx.x;
  if (i < n) p[i] = 0;
}

// ---------- histogram of col ----------
__global__ void count_kernel(const int* __restrict__ col, int* __restrict__ counts, int E) {
  int e = blockIdx.x * blockDim.x + threadIdx.x;
  if (e < E) atomicAdd(&counts[col[e]], 1);
}

// ---------- 3-kernel exclusive scan over N1 = N+1 elements ----------
__global__ __launch_bounds__(1024) void scan1_kernel(const int* __restrict__ counts,
                                                     int* __restrict__ offsets,
                                                     int* __restrict__ bsum, int N, int N1) {
  __shared__ int sh[1024];
  int tid = threadIdx.x;
  int i = blockIdx.x * 1024 + tid;
  int v = (i < N) ? counts[i] : 0;
  sh[tid] = v;
  __syncthreads();
  for (int off = 1; off < 1024; off <<= 1) {
    int tv = (tid >= off) ? sh[tid - off] : 0;
    __syncthreads();
    sh[tid] += tv;
    __syncthreads();
  }
  if (i < N1) offsets[i] = sh[tid] - v;
  if (tid == 1023) bsum[blockIdx.x] = sh[1023];
}

__global__ __launch_bounds__(128) void scan2_kernel(int* __restrict__ bsum, int NB) {
  __shared__ int sh[128];
  int tid = threadIdx.x;
  int v = (tid < NB) ? bsum[tid] : 0;
  sh[tid] = v;
  __syncthreads();
  for (int off = 1; off < 128; off <<= 1) {
    int tv = (tid >= off) ? sh[tid - off] : 0;
    __syncthreads();
    sh[tid] += tv;
    __syncthreads();
  }
  if (tid < NB) bsum[tid] = sh[tid] - v;
}

__global__ __launch_bounds__(1024) void scan3_kernel(int* __restrict__ offsets,
                                                     const int* __restrict__ bsum,
                                                     int* __restrict__ cursor, int N, int N1) {
  int i = blockIdx.x * 1024 + threadIdx.x;
  if (i < N1) {
    int o = offsets[i] + bsum[blockIdx.x];
    offsets[i] = o;
    if (i < N) cursor[i] = o;
  }
}

// ---------- prep: a_self (log2 domain, ba2 dropped) + permuted f16-pair ba1/Wa2 tables ----
__global__ __launch_bounds__(64) void prep_kernel(const float* __restrict__ ba1,
                                                  const float* __restrict__ Wa2,
                                                  float* __restrict__ a_self,
                                                  unsigned* __restrict__ ba1p,
                                                  unsigned* __restrict__ wa2p) {
  int l = threadIdx.x;  // stored word index s
  int d = pilo(l);
  ba1p[l] = pkrtz(ba1[d], ba1[d + 16]);
  wa2p[l] = pkrtz(Wa2[d] * LOG2E, Wa2[d + 16] * LOG2E);
  float t1 = ba1[l], t2 = ba1[l + 64];
  float v = LRELU(t1) * Wa2[l] + LRELU(t2) * Wa2[l + 64];
#pragma unroll
  for (int off = 32; off > 0; off >>= 1) v += __shfl_xor(v, off);
  if (l == 0) *a_self = v * LOG2E;
}

// ---------- CSR build: scatter rol values grouped by col ----------
__global__ void scatter_kernel(const int* __restrict__ rol, const int* __restrict__ col,
                               int* __restrict__ cursor, int* __restrict__ csr_rol, int E) {
  int e = blockIdx.x * blockDim.x + threadIdx.x;
  if (e < E) {
    int pos = atomicAdd(&cursor[col[e]], 1);
    csr_rol[pos] = rol[e];
  }
}

// ---------- per-edge logit from packed f16 row ----------
__device__ __forceinline__ float logit8(half8 pp, half8 pm, const H8U4& ww) {
  half8 t = pp - pm;
  half8 lt = __builtin_elementwise_max(t, t * (_Float16)0.01f);
  H8U4 L;
  L.h = lt;
  float v = FDOT2(L.p[0], ww.p[0], 0.0f);
  v = FDOT2(L.p[1], ww.p[1], v);
  v = FDOT2(L.p[2], ww.p[2], v);
  v = FDOT2(L.p[3], ww.p[3], v);
  return v;
}

// ---------- fused flash node kernel: wave/node; 4 independent 16-lane groups ----------
// Group g owns edges j0+g, j0+g+4, ... with its own (m, s, acc[8]); combine once per node.
// embP row (512B): uint4[0..15] = emb f16 pairs (permuted), uint4[16..31] = P f16 pairs.
__global__ __launch_bounds__(256) void fused_kernel(
    const int* __restrict__ offsets, const int* __restrict__ csr_rol,
    const uint4* __restrict__ embP4, const unsigned* __restrict__ ba1p,
    const unsigned* __restrict__ wa2p, const float* __restrict__ a_self_p,
    uint4* __restrict__ msgb4, int N, int nwt) {
  const int lane = threadIdx.x & 63;
  const int q = lane & 15;
  const int g = lane >> 4;
  const int wid = blockIdx.x * (blockDim.x >> 6) + (threadIdx.x >> 6);
  H8U4 bb, ww;
  bb.u = reinterpret_cast<const uint4*>(ba1p)[q];
  ww.u = reinterpret_cast<const uint4*>(wa2p)[q];
  const float aself = *a_self_p;

  for (int n = wid; n < N; n += nwt) {
    int j0 = offsets[n], j1 = offsets[n + 1];
    const uint4* rowN = embP4 + (size_t)n * 32;
    H8U4 ue, up;
    ue.u = rowN[q];
    up.u = rowN[16 + q];
    half8 pm = up.h - bb.h;  // P_col - ba1 (logit uses P_r - pm)
    float acc[8];
#pragma unroll
    for (int k = 0; k < 8; ++k) acc[k] = 0.25f * (float)ue.h[k];
    float m = aself, s = 0.25f;  // self-loop split evenly across 4 groups

    int j = j0 + g;
    for (; j + 4 < j1; j += 8) {  // 2 edges of this group in flight
      int r0 = csr_rol[j], r1 = csr_rol[j + 4];
      const uint4* R0 = embP4 + (size_t)r0 * 32;
      const uint4* R1 = embP4 + (size_t)r1 * 32;
      H8U4 pe0, pp0, pe1, pp1;
      pe0.u = R0[q];
      pp0.u = R0[16 + q];
      pe1.u = R1[q];
      pp1.u = R1[16 + q];
      float v0 = logit8(pp0.h, pm, ww);
      float v1 = logit8(pp1.h, pm, ww);
      v0 += __shfl_xor(v0, 1);
      v1 += __shfl_xor(v1, 1);
      v0 += __shfl_xor(v0, 2);
      v1 += __shfl_xor(v1, 2);
      v0 += __shfl_xor(v0, 4);
      v1 += __shfl_xor(v1, 4);
      v0 += __shfl_xor(v0, 8);
      v1 += __shfl_xor(v1, 8);
      float d0 = v0 - m, d1 = v1 - m;
      float dm = fmaxf(d0, d1);
      if (dm <= 8.0f) {  // defer-max fast path: weights bounded by 2^8, f32 acc is safe
        float e0 = __builtin_exp2f(d0), e1 = __builtin_exp2f(d1);
        s += e0 + e1;
#pragma unroll
        for (int k = 0; k < 8; ++k) acc[k] += e0 * (float)pe0.h[k] + e1 * (float)pe1.h[k];
      } else {
        float c = __builtin_exp2f(-dm);
        float e0 = __builtin_exp2f(d0 - dm), e1 = __builtin_exp2f(d1 - dm);
        s = s * c + e0 + e1;
#pragma unroll
        for (int k = 0; k < 8; ++k)
          acc[k] = acc[k] * c + e0 * (float)pe0.h[k] + e1 * (float)pe1.h[k];
        m += dm;
      }
    }
    if (j < j1) {  // tail: at most one edge per group
      int r = csr_rol[j];
      const uint4* R = embP4 + (size_t)r * 32;
      H8U4 pe, pp;
      pe.u = R[q];
      pp.u = R[16 + q];
      float v = logit8(pp.h, pm, ww);
      v += __shfl_xor(v, 1);
      v += __shfl_xor(v, 2);
      v += __shfl_xor(v, 4);
      v += __shfl_xor(v, 8);
      float d = v - m;
      if (d <= 8.0f) {
        float e = __builtin_exp2f(d);
        s += e;
#pragma unroll
        for (int k = 0; k < 8; ++k) acc[k] += e * (float)pe.h[k];
      } else {
        float c = __builtin_exp2f(-d);
        s = s * c + 1.0f;
#pragma unroll
        for (int k = 0; k < 8; ++k) acc[k] = acc[k] * c + (float)pe.h[k];
        m = v;
      }
    }
    // cross-group combine (once per node)
    float mo = fmaxf(m, __shfl_xor(m, 16));
    mo = fmaxf(mo, __shfl_xor(mo, 32));
    float c = __builtin_exp2f(m - mo);
    float st = s * c;
    st += __shfl_xor(st, 16);
    st += __shfl_xor(st, 32);
#pragma unroll
    for (int k = 0; k < 8; ++k) {
      float a = acc[k] * c;
      a += __shfl_xor(a, 16);
      a += __shfl_xor(a, 32);
      acc[k] = a;
    }
    float inv = 1.0f / st;
    if (g == 0) {
      uint4 o;
      o.x = pkrtz(acc[0] * inv, acc[1] * inv);
      o.y = pkrtz(acc[2] * inv, acc[3] * inv);
      o.z = pkrtz(acc[4] * inv, acc[5] * inv);
      o.w = pkrtz(acc[6] * inv, acc[7] * inv);
      msgb4[(size_t)n * 16 + q] = o;
    }
  }
}

extern "C" void kernel_launch(void* const* d_in, const int* in_sizes, int n_in,
                              void* d_out, int out_size, void* d_ws, size_t ws_size,
                              hipStream_t stream) {
  const float* x     = (const float*)d_in[0];
  const int*   ei    = (const int*)d_in[1];
  const float* W_emb = (const float*)d_in[2];
  const float* b_emb = (const float*)d_in[3];
  const float* Wa1   = (const float*)d_in[4];
  const float* ba1   = (const float*)d_in[5];
  const float* Wa2   = (const float*)d_in[6];
  // d_in[7] = ba2: cancels in segment softmax, unused
  const float* W_upd = (const float*)d_in[8];
  const float* b_upd = (const float*)d_in[9];
  float* out = (float*)d_out;

  const int N = in_sizes[0] / 128;
  const int E = in_sizes[1] / 2;
  const int* rol = ei;
  const int* col = ei + E;

  char* base = (char*)d_ws;
  size_t off = 0;
  auto carve = [&](size_t bytes) {
    void* p = base + off;
    off = (off + bytes + 255) & ~(size_t)255;
    return p;
  };
  unsigned*  embP  = (unsigned*)carve((size_t)N * 128 * 4);   // [emb|P] f16 pairs, 512B/row
  _Float16*  x16   = (_Float16*)carve((size_t)N * 128 * 2);   // x as f16
  unsigned*  msgb  = (unsigned*)carve((size_t)N * 64 * 4);    // msg f16 pairs, 256B/row
  _Float16*  WtA   = (_Float16*)carve(256 * 128 * 2);
  _Float16*  WtU   = (_Float16*)carve(128 * 128 * 2);
  unsigned*  ba1p  = (unsigned*)carve(64 * 4);
  unsigned*  wa2p  = (unsigned*)carve(64 * 4);
  int*       csr_rol = (int*)carve((size_t)E * 4);
  float*     a_self  = (float*)carve(16);
  int*       counts  = (int*)carve((size_t)N * 4);
  int*       offsets = (int*)carve((size_t)(N + 1) * 4);
  int*       cursor  = (int*)carve((size_t)N * 4);
  int*       bsum    = (int*)carve(128 * 4);
  (void)ws_size;

  const int N1 = N + 1;
  const int NB = (N1 + 1023) / 1024;  // 98 for N=100000 (must be <=128)
  const int SBLK = 2048;              // fused grid (8192 waves)
  const int NWT = SBLK * 4;

  zero_kernel<<<(N + 255) / 256, 256, 0, stream>>>(counts, N);
  wtrans_kernel<<<192, 256, 0, stream>>>(W_emb, Wa1, W_upd, WtA, WtU);
  xcvt_kernel<<<(N * 16 + 255) / 256, 256, 0, stream>>>((const float4*)x, (uint4*)x16, N * 16);

  gemm_embP_kernel<<<(N + 31) / 32, 256, 0, stream>>>(x16, WtA, b_emb, embP, N);

  count_kernel<<<(E + 255) / 256, 256, 0, stream>>>(col, counts, E);
  scan1_kernel<<<NB, 1024, 0, stream>>>(counts, offsets, bsum, N, N1);
  scan2_kernel<<<1, 128, 0, stream>>>(bsum, NB);
  scan3_kernel<<<NB, 1024, 0, stream>>>(offsets, bsum, cursor, N, N1);
  prep_kernel<<<1, 64, 0, stream>>>(ba1, Wa2, a_self, ba1p, wa2p);
  scatter_kernel<<<(E + 255) / 256, 256, 0, stream>>>(rol, col, cursor, csr_rol, E);

  fused_kernel<<<SBLK, 256, 0, stream>>>(offsets, csr_rol, (const uint4*)embP, ba1p, wa2p,
                                         a_self, (uint4*)msgb, N, NWT);

  gemm_out_kernel<<<(N + 63) / 64, 256, 0, stream>>>((const _Float16*)msgb, WtU, b_upd, out, N);
}